// Round 7
// baseline (639.885 us; speedup 1.0000x reference)
//
#include <hip/hip_runtime.h>
#include <hip/hip_fp16.h>

// ---------------------------------------------------------------------------
// Ctx_MHAtt: out = ((softmax(LN_k((QE·KH^T)))) · VH) · Wm^T + bm
// where QE = (q·Wq^T + bq + tanh(tau)·CU) * (1/sqrt(128))/(1+tanh(tau))
//       CU = Wup · (c·Wc^T + bc)   (caption upsample KC=32 -> NQ)
// B=8, NQ=NK=HD=1024, H=8, HS=128, KC=32
// R7 = R4 resubmission (R4/R5/R6 were GPUAcquisitionTimeout; never ran):
// attn_k rebuilt — latency-bound fix (was MfmaUtil 5.4%, Occ 22.7%):
// 4-deep explicit load pipelines, no-max shifted softmax, LDS 33.5KB.
// ---------------------------------------------------------------------------

typedef _Float16 f16;
typedef _Float16 f16x8 __attribute__((ext_vector_type(8)));
typedef _Float16 f16x4 __attribute__((ext_vector_type(4)));
typedef float    f32x4 __attribute__((ext_vector_type(4)));

#define B_  8
#define NQ_ 1024
#define NK_ 1024
#define HD_ 1024
#define H_  8
#define HS_ 128
#define KC_ 32

__device__ __forceinline__ void g2lds16(const void* g, void* l) {
    __builtin_amdgcn_global_load_lds((const __attribute__((address_space(1))) void*)g,
                                     (__attribute__((address_space(3))) void*)l, 16, 0, 0);
}

// --------------------------- ws-too-small sentinel ---------------------------
__global__ __launch_bounds__(256) void fill_sentinel(float* __restrict__ out, int n) {
    int i = blockIdx.x * 256 + threadIdx.x;
    if (i < n) out[i] = 12345.0f;
}

// --------------------------- fp32 -> fp16 convert ---------------------------
__global__ __launch_bounds__(256) void cvt_f32_f16(const float* __restrict__ in,
                                                   f16* __restrict__ out, int n4) {
    int i = blockIdx.x * 256 + threadIdx.x;
    if (i >= n4) return;
    float4 v = ((const float4*)in)[i];
    f16x4 o;
    o[0] = (f16)v.x; o[1] = (f16)v.y; o[2] = (f16)v.z; o[3] = (f16)v.w;
    ((f16x4*)out)[i] = o;
}

// --------------------------- NT GEMM: C = A · B^T ---------------------------
// (unchanged from R3 — profiled next round once attn stops dominating)
template <int MODE>
__global__ __launch_bounds__(256) void gemm_nt(
    const f16* __restrict__ A, long long sA,
    const f16* __restrict__ B, long long sB,
    void* __restrict__ Cv, long long sC,
    int M, int N, int K,
    const float* __restrict__ bias,
    const f16* __restrict__ extra, long long sE,
    const float* __restrict__ taup)
{
    __shared__ __align__(16) f16 As[128 * 32];
    __shared__ __align__(16) f16 Bs[128 * 32];
    const int bz = blockIdx.z;
    const f16* Ab = A + (size_t)bz * sA;
    const f16* Bb = B + (size_t)bz * sB;
    const int row0 = blockIdx.y * 128, col0 = blockIdx.x * 128;
    const int tid = threadIdx.x, wave = tid >> 6, lane = tid & 63;
    const int g = lane >> 4, li = lane & 15;
    const int wr = wave >> 1, wc = wave & 1;

    f32x4 acc[4][4];
#pragma unroll
    for (int i = 0; i < 4; i++)
#pragma unroll
        for (int j = 0; j < 4; j++) acc[i][j] = (f32x4){0.f, 0.f, 0.f, 0.f};

    for (int k0 = 0; k0 < K; k0 += 32) {
#pragma unroll
        for (int i = 0; i < 2; i++) {
            int slot = i * 256 + tid;          // 16B slot in [0,512)
            int rr = slot >> 2, cc8 = (slot & 3) << 3;
            int ra = row0 + rr;
            if (MODE == 0 && ra >= M) ra = M - 1;   // clamp (stores guarded)
            g2lds16(Ab + (size_t)ra * K + k0 + cc8, As + (size_t)(i * 256 + wave * 64) * 8);
            g2lds16(Bb + (size_t)(col0 + rr) * K + k0 + cc8, Bs + (size_t)(i * 256 + wave * 64) * 8);
        }
        __syncthreads();
        f16x8 af[4], bf[4];
#pragma unroll
        for (int i = 0; i < 4; i++) af[i] = *(const f16x8*)&As[(wr * 64 + i * 16 + li) * 32 + g * 8];
#pragma unroll
        for (int j = 0; j < 4; j++) bf[j] = *(const f16x8*)&Bs[(wc * 64 + j * 16 + li) * 32 + g * 8];
#pragma unroll
        for (int i = 0; i < 4; i++)
#pragma unroll
            for (int j = 0; j < 4; j++)
                acc[i][j] = __builtin_amdgcn_mfma_f32_16x16x32_f16(af[i], bf[j], acc[i][j], 0, 0, 0);
        __syncthreads();
    }

    float tv = 0.f, qscale = 0.f;
    if constexpr (MODE == 3) {
        tv = tanhf(taup[0]);
        qscale = 0.08838834764831845f / (1.0f + tv);   // (1/sqrt(128)) / (1+t)
    }
#pragma unroll
    for (int i = 0; i < 4; i++) {
#pragma unroll
        for (int j = 0; j < 4; j++) {
            int cc = col0 + wc * 64 + j * 16 + li;
            float bcol = (MODE == 2) ? 0.f : bias[cc];
#pragma unroll
            for (int r = 0; r < 4; r++) {
                int row = row0 + wr * 64 + i * 16 + g * 4 + r;
                if (MODE == 0 && row >= M) continue;
                float v = acc[i][j][r];
                if constexpr (MODE == 2) v += bias[row]; else v += bcol;
                size_t idx = (size_t)bz * sC + (size_t)row * N + cc;
                if constexpr (MODE == 0) ((float*)Cv)[idx] = v;
                else if constexpr (MODE == 1 || MODE == 2) ((f16*)Cv)[idx] = (f16)v;
                else if constexpr (MODE == 3) {
                    v = (v + tv * (float)extra[(size_t)bz * sE + (size_t)row * N + cc]) * qscale;
                    ((f16*)Cv)[idx] = (f16)v;
                } else ((float*)Cv)[idx] = v;   // MODE 4
            }
        }
    }
}

// --------------------------- caption upsample ---------------------------
__global__ __launch_bounds__(256) void upsample_k(const float* __restrict__ Wup,
                                                  const float* __restrict__ CH,
                                                  f16* __restrict__ CU) {
    const int u = blockIdx.x, b = blockIdx.y;
    const float* ch = CH + (size_t)b * KC_ * HD_;
    float w[KC_];
#pragma unroll
    for (int c = 0; c < KC_; c++) w[c] = Wup[u * KC_ + c];
    f16* out = CU + ((size_t)b * NQ_ + u) * HD_;
#pragma unroll
    for (int t = 0; t < 4; t++) {
        int i = threadIdx.x + t * 256;
        float acc = 0.f;
#pragma unroll
        for (int c = 0; c < KC_; c++) acc += w[c] * ch[c * HD_ + i];
        out[i] = (f16)acc;
    }
}

// --------------------------- fused attention (v2) ---------------------------
// grid (NQ/16, H, B); 4 waves; wave w owns keys [w*256, (w+1)*256).
// S in registers; LN stats via shfl + LDS cross-wave; NO max pass (LN output
// is standardized -> fixed shift exp(x-4), softmax-invariant); single
// LN+exp+Pwrite pass; 2 barriers; 4-deep explicit load pipelines.
#define MFMA16(A_, B_, C_) __builtin_amdgcn_mfma_f32_16x16x32_f16(A_, B_, C_, 0, 0, 0)

__global__ void attn_k(
    const f16* __restrict__ QE,   // [B,NQ,HD]  (scaled effective query)
    const f16* __restrict__ KH,   // [B,NK,HD]
    const f16* __restrict__ VT,   // [B,HD,NK]  (v-heads transposed)
    const float* __restrict__ lnw_g, const float* __restrict__ lnb_g,
    f16* __restrict__ ATT)        // [B,NQ,HD]
{
    __shared__ __align__(16) f16 Plds[16 * NK_];   // 32KB, XOR-swizzled 16B chunks
    __shared__ float redS[4][16], redQ[4][16], redL[4][16];

    const int tid = threadIdx.x;
    const int wave = tid >> 6, lane = tid & 63, g = lane >> 4, li = lane & 15;
    const int b = blockIdx.z, h = blockIdx.y, q0 = blockIdx.x * 16;

    // Q fragments: A_op row = li, k = g*8 + j within each 32-wide k-step
    const f16* qp = QE + (size_t)(b * NQ_ + q0 + li) * HD_ + h * HS_ + g * 8;
    f16x8 a[4];
#pragma unroll
    for (int ks = 0; ks < 4; ks++) a[ks] = *(const f16x8*)(qp + ks * 32);

    // ---- QK^T: 32 half-j units, 4-deep register pipeline ----
    const f16* kp = KH + (size_t)(b * NK_ + wave * 256 + li) * HD_ + h * HS_ + g * 8;
    f32x4 s[16];
#pragma unroll
    for (int j = 0; j < 16; j++) s[j] = (f32x4){0.f, 0.f, 0.f, 0.f};

    f16x8 kbA0, kbA1, kbB0, kbB1, kbC0, kbC1, kbD0, kbD1;
#define QK_LD(BUF, U) do { \
        const f16* _p = kp + (size_t)((U) >> 1) * 16 * HD_ + ((U) & 1) * 64; \
        kb##BUF##0 = *(const f16x8*)(_p); \
        kb##BUF##1 = *(const f16x8*)(_p + 32); \
    } while (0)
#define QK_FMA(BUF, U) do { \
        __builtin_amdgcn_s_setprio(1); \
        s[(U) >> 1] = MFMA16(a[((U) & 1) * 2],     kb##BUF##0, s[(U) >> 1]); \
        s[(U) >> 1] = MFMA16(a[((U) & 1) * 2 + 1], kb##BUF##1, s[(U) >> 1]); \
        __builtin_amdgcn_s_setprio(0); \
    } while (0)

    QK_LD(A, 0); QK_LD(B, 1); QK_LD(C, 2); QK_LD(D, 3);
#pragma unroll
    for (int u = 0; u < 32; u += 4) {
        QK_FMA(A, u);     if (u + 4 < 32) QK_LD(A, u + 4);
        QK_FMA(B, u + 1); if (u + 5 < 32) QK_LD(B, u + 5);
        QK_FMA(C, u + 2); if (u + 6 < 32) QK_LD(C, u + 6);
        QK_FMA(D, u + 3); if (u + 7 < 32) QK_LD(D, u + 7);
    }
    // lane holds S[row=g*4+r][key=wave*256+j*16+li]

    // ---- ln weights into registers (off QK^T register peak) ----
    float lw[16], lb[16];
#pragma unroll
    for (int j = 0; j < 16; j++) {
        int key = wave * 256 + j * 16 + li;
        lw[j] = lnw_g[key];
        lb[j] = lnb_g[key];
    }

    // ---- mean / var over keys ----
    float ps[4] = {0, 0, 0, 0}, pq[4] = {0, 0, 0, 0};
#pragma unroll
    for (int j = 0; j < 16; j++)
#pragma unroll
        for (int r = 0; r < 4; r++) { float x = s[j][r]; ps[r] += x; pq[r] += x * x; }
#pragma unroll
    for (int m = 1; m < 16; m <<= 1)
#pragma unroll
        for (int r = 0; r < 4; r++) { ps[r] += __shfl_xor(ps[r], m, 64); pq[r] += __shfl_xor(pq[r], m, 64); }
    if (li == 0)
#pragma unroll
        for (int r = 0; r < 4; r++) { redS[wave][g * 4 + r] = ps[r]; redQ[wave][g * 4 + r] = pq[r]; }
    __syncthreads();   // barrier 1: stats ready

    float mu[4], rs[4];
#pragma unroll
    for (int r = 0; r < 4; r++) {
        int row = g * 4 + r;
        float s1 = redS[0][row] + redS[1][row] + redS[2][row] + redS[3][row];
        float s2 = redQ[0][row] + redQ[1][row] + redQ[2][row] + redQ[3][row];
        float m_ = s1 * (1.f / 1024.f);
        mu[r] = m_;
        rs[r] = rsqrtf(s2 * (1.f / 1024.f) - m_ * m_ + 1e-5f);
    }

    // ---- fused LN + shifted exp + row-sum + swizzled P write (one pass) ----
    // LN output is standardized (row mean=b, var=w^2): exp(x-4) never overflows
    // fp16 (clamp at 11 for safety) and softmax is shift-invariant.
    float sm[4] = {0, 0, 0, 0};
#pragma unroll
    for (int j = 0; j < 16; j++) {
        int key = wave * 256 + j * 16 + li;
        int chunk = key >> 3, sub = key & 7;
#pragma unroll
        for (int r = 0; r < 4; r++) {
            int row = g * 4 + r;
            float x = (s[j][r] - mu[r]) * rs[r] * lw[j] + lb[j];
            float e = __expf(fminf(x, 11.f) - 4.f);
            sm[r] += e;
            Plds[row * NK_ + ((chunk ^ (row & 7)) << 3) + sub] = (f16)e;
        }
    }
#pragma unroll
    for (int m = 1; m < 16; m <<= 1)
#pragma unroll
        for (int r = 0; r < 4; r++) sm[r] += __shfl_xor(sm[r], m, 64);
    if (li == 0)
#pragma unroll
        for (int r = 0; r < 4; r++) redL[wave][g * 4 + r] = sm[r];
    __syncthreads();   // barrier 2: P + partial sums ready

    float ls[4];
#pragma unroll
    for (int r = 0; r < 4; r++) {
        int row = g * 4 + r;
        ls[r] = redL[0][row] + redL[1][row] + redL[2][row] + redL[3][row];
    }

    // ---- PV: 32 ks units, 4-deep pipeline, split accumulators ----
    const f16* vp = VT + (size_t)(b * HD_ + h * HS_ + wave * 32 + li) * NK_ + g * 8;
    f32x4 o0a = (f32x4){0.f, 0.f, 0.f, 0.f}, o0b = o0a, o1a = o0a, o1b = o0a;
    f16x8 paA, v0A, v1A, paB, v0B, v1B, paC, v0C, v1C, paD, v0D, v1D;
#define PV_LD(BUF, U) do { \
        pa##BUF = *(const f16x8*)&Plds[(size_t)li * NK_ + ((((U) * 4 + g) ^ (li & 7)) << 3)]; \
        v0##BUF = *(const f16x8*)(vp + (size_t)(U) * 32); \
        v1##BUF = *(const f16x8*)(vp + (size_t)16 * NK_ + (size_t)(U) * 32); \
    } while (0)
#define PV_FMA(BUF, OA, OB) do { \
        __builtin_amdgcn_s_setprio(1); \
        OA = MFMA16(pa##BUF, v0##BUF, OA); \
        OB = MFMA16(pa##BUF, v1##BUF, OB); \
        __builtin_amdgcn_s_setprio(0); \
    } while (0)

    PV_LD(A, 0); PV_LD(B, 1); PV_LD(C, 2); PV_LD(D, 3);
#pragma unroll
    for (int u = 0; u < 32; u += 4) {
        PV_FMA(A, o0a, o1a); if (u + 4 < 32) PV_LD(A, u + 4);
        PV_FMA(B, o0b, o1b); if (u + 5 < 32) PV_LD(B, u + 5);
        PV_FMA(C, o0a, o1a); if (u + 6 < 32) PV_LD(C, u + 6);
        PV_FMA(D, o0b, o1b); if (u + 7 < 32) PV_LD(D, u + 7);
    }

    f16* op = ATT + (size_t)(b * NQ_ + q0) * HD_ + h * HS_ + wave * 32 + li;
#pragma unroll
    for (int r = 0; r < 4; r++) {
        int row = g * 4 + r;
        float inv = 1.f / ls[r];
        op[(size_t)row * HD_]      = (f16)((o0a[r] + o0b[r]) * inv);
        op[(size_t)row * HD_ + 16] = (f16)((o1a[r] + o1b[r]) * inv);
    }
}

// --------------------------- launcher ---------------------------
extern "C" void kernel_launch(void* const* d_in, const int* in_sizes, int n_in,
                              void* d_out, int out_size, void* d_ws, size_t ws_size,
                              hipStream_t stream) {
    const float* v   = (const float*)d_in[0];
    const float* k   = (const float*)d_in[1];
    const float* q   = (const float*)d_in[2];
    const float* c   = (const float*)d_in[3];
    const float* Wv  = (const float*)d_in[4];
    const float* bv  = (const float*)d_in[5];
    const float* Wk  = (const float*)d_in[6];
    const float* bk  = (const float*)d_in[7];
    const float* Wq  = (const float*)d_in[8];
    const float* bq  = (const float*)d_in[9];
    const float* Wc  = (const float*)d_in[10];
    const float* bc  = (const float*)d_in[11];
    const float* Wm  = (const float*)d_in[12];
    const float* bm  = (const float*)d_in[13];
    const float* Wup = (const float*)d_in[14];
    const float* lnw = (const float*)d_in[15];
    const float* lnb = (const float*)d_in[16];
    const float* tau = (const float*)d_in[17];

    const size_t NE  = (size_t)B_ * NK_ * HD_;   // 8M elements
    const size_t NW  = (size_t)HD_ * HD_;        // 1M
    const size_t NC  = (size_t)B_ * KC_ * HD_;   // 256K

    const size_t REQUIRED = 95944704;            // 91.5 MB
    if (ws_size < REQUIRED) {                    // diagnostic sentinel, no fault
        fill_sentinel<<<dim3((out_size + 255) / 256), dim3(256), 0, stream>>>((float*)d_out, out_size);
        return;
    }
    char* ws = (char*)d_ws;
    f16*  k16  = (f16*)(ws + 0);                 // slotA: k16 -> QE
    f16*  QE   = (f16*)(ws + 0);
    f16*  v16  = (f16*)(ws + 16777216);          // slotB: v16 -> CU16
    f16*  CU16 = (f16*)(ws + 16777216);
    f16*  q16  = (f16*)(ws + 33554432);          // slotC: q16 -> ATT
    f16*  ATT  = (f16*)(ws + 33554432);
    f16*  c16  = (f16*)(ws + 50331648);
    float* CHf = (float*)(ws + 50855936);
    f16*  wk16 = (f16*)(ws + 51904512);
    f16*  wq16 = (f16*)(ws + 54001664);
    f16*  wv16 = (f16*)(ws + 56098816);
    f16*  wc16 = (f16*)(ws + 58195968);
    f16*  wm16 = (f16*)(ws + 60293120);
    f16*  KH   = (f16*)(ws + 62390272);
    f16*  VT   = (f16*)(ws + 79167488);

    dim3 blk(256);
    auto cvt = [&](const float* in, f16* out, size_t n) {
        cvt_f32_f16<<<dim3((unsigned)(n / 1024)), blk, 0, stream>>>(in, out, (int)(n / 4));
    };
    cvt(k, k16, NE);
    cvt(v, v16, NE);
    cvt(q, q16, NE);
    cvt(c, c16, NC);
    cvt(Wk, wk16, NW);
    cvt(Wq, wq16, NW);
    cvt(Wv, wv16, NW);
    cvt(Wc, wc16, NW);
    cvt(Wm, wm16, NW);

    // KH[b,key,hd] = k·Wk^T + bk
    gemm_nt<1><<<dim3(8, 8, 8), blk, 0, stream>>>(k16, (long long)NK_ * HD_, wk16, 0,
        KH, (long long)NK_ * HD_, NK_, HD_, HD_, bk, nullptr, 0, nullptr);
    // VT[b,hd,key] = (v·Wv^T + bv)^T  (Wv as A-operand)
    gemm_nt<2><<<dim3(8, 8, 8), blk, 0, stream>>>(wv16, 0, v16, (long long)NK_ * HD_,
        VT, (long long)HD_ * NK_, HD_, NK_, HD_, bv, nullptr, 0, nullptr);
    // CH[b,c,hd] = c·Wc^T + bc (fp32)
    gemm_nt<0><<<dim3(8, 1, 8), blk, 0, stream>>>(c16, (long long)KC_ * HD_, wc16, 0,
        CHf, (long long)KC_ * HD_, KC_, HD_, HD_, bc, nullptr, 0, nullptr);
    // CU = Wup · CH  (f16)
    upsample_k<<<dim3(NQ_, B_), blk, 0, stream>>>(Wup, CHf, CU16);
    // QE[b,q,hd] = (q·Wq^T + bq + t·CU) * inv_sqrt_d/(1+t)
    gemm_nt<3><<<dim3(8, 8, 8), blk, 0, stream>>>(q16, (long long)NQ_ * HD_, wq16, 0,
        QE, (long long)NQ_ * HD_, NQ_, HD_, HD_, bq, CU16, (long long)NQ_ * HD_, tau);
    // fused attention -> ATT[b,q,hd] (f16)
    attn_k<<<dim3(NQ_ / 16, H_, B_), blk, 0, stream>>>(QE, KH, VT, lnw, lnb, ATT);
    // out = ATT·Wm^T + bm (fp32)
    gemm_nt<4><<<dim3(8, 8, 8), blk, 0, stream>>>(ATT, (long long)NQ_ * HD_, wm16, 0,
        d_out, (long long)NQ_ * HD_, NQ_, HD_, HD_, bm, nullptr, 0, nullptr);
}

// Round 8
// 570.944 us; speedup vs baseline: 1.1207x; 1.1207x over previous
//
#include <hip/hip_runtime.h>
#include <hip/hip_fp16.h>

// ---------------------------------------------------------------------------
// Ctx_MHAtt: out = ((softmax(LN_k((QE·KH^T)))) · VH) · Wm^T + bm
// R8: attn_k v3 — R7 postmortem showed L3-BW bound (2.1GB @ 7.9TB/s, all
// pipes <15%, occupancy-insensitive). Fix: QBLK=32 (traffic 2.1->1.06GB) +
// XCD swizzle (per-(b,h) KV set pinned to one XCD's L2). 8 waves, S in regs,
// P in 64KB LDS (stats alias first 3KB, 4-barrier schedule).
// ---------------------------------------------------------------------------

typedef _Float16 f16;
typedef _Float16 f16x8 __attribute__((ext_vector_type(8)));
typedef _Float16 f16x4 __attribute__((ext_vector_type(4)));
typedef float    f32x4 __attribute__((ext_vector_type(4)));

#define B_  8
#define NQ_ 1024
#define NK_ 1024
#define HD_ 1024
#define H_  8
#define HS_ 128
#define KC_ 32

__device__ __forceinline__ void g2lds16(const void* g, void* l) {
    __builtin_amdgcn_global_load_lds((const __attribute__((address_space(1))) void*)g,
                                     (__attribute__((address_space(3))) void*)l, 16, 0, 0);
}

// --------------------------- ws-too-small sentinel ---------------------------
__global__ __launch_bounds__(256) void fill_sentinel(float* __restrict__ out, int n) {
    int i = blockIdx.x * 256 + threadIdx.x;
    if (i < n) out[i] = 12345.0f;
}

// --------------------------- fp32 -> fp16 convert ---------------------------
__global__ __launch_bounds__(256) void cvt_f32_f16(const float* __restrict__ in,
                                                   f16* __restrict__ out, int n4) {
    int i = blockIdx.x * 256 + threadIdx.x;
    if (i >= n4) return;
    float4 v = ((const float4*)in)[i];
    f16x4 o;
    o[0] = (f16)v.x; o[1] = (f16)v.y; o[2] = (f16)v.z; o[3] = (f16)v.w;
    ((f16x4*)out)[i] = o;
}

// --------------------------- NT GEMM: C = A · B^T ---------------------------
// (unchanged; profiled next round)
template <int MODE>
__global__ __launch_bounds__(256) void gemm_nt(
    const f16* __restrict__ A, long long sA,
    const f16* __restrict__ B, long long sB,
    void* __restrict__ Cv, long long sC,
    int M, int N, int K,
    const float* __restrict__ bias,
    const f16* __restrict__ extra, long long sE,
    const float* __restrict__ taup)
{
    __shared__ __align__(16) f16 As[128 * 32];
    __shared__ __align__(16) f16 Bs[128 * 32];
    const int bz = blockIdx.z;
    const f16* Ab = A + (size_t)bz * sA;
    const f16* Bb = B + (size_t)bz * sB;
    const int row0 = blockIdx.y * 128, col0 = blockIdx.x * 128;
    const int tid = threadIdx.x, wave = tid >> 6, lane = tid & 63;
    const int g = lane >> 4, li = lane & 15;
    const int wr = wave >> 1, wc = wave & 1;

    f32x4 acc[4][4];
#pragma unroll
    for (int i = 0; i < 4; i++)
#pragma unroll
        for (int j = 0; j < 4; j++) acc[i][j] = (f32x4){0.f, 0.f, 0.f, 0.f};

    for (int k0 = 0; k0 < K; k0 += 32) {
#pragma unroll
        for (int i = 0; i < 2; i++) {
            int slot = i * 256 + tid;
            int rr = slot >> 2, cc8 = (slot & 3) << 3;
            int ra = row0 + rr;
            if (MODE == 0 && ra >= M) ra = M - 1;
            g2lds16(Ab + (size_t)ra * K + k0 + cc8, As + (size_t)(i * 256 + wave * 64) * 8);
            g2lds16(Bb + (size_t)(col0 + rr) * K + k0 + cc8, Bs + (size_t)(i * 256 + wave * 64) * 8);
        }
        __syncthreads();
        f16x8 af[4], bf[4];
#pragma unroll
        for (int i = 0; i < 4; i++) af[i] = *(const f16x8*)&As[(wr * 64 + i * 16 + li) * 32 + g * 8];
#pragma unroll
        for (int j = 0; j < 4; j++) bf[j] = *(const f16x8*)&Bs[(wc * 64 + j * 16 + li) * 32 + g * 8];
#pragma unroll
        for (int i = 0; i < 4; i++)
#pragma unroll
            for (int j = 0; j < 4; j++)
                acc[i][j] = __builtin_amdgcn_mfma_f32_16x16x32_f16(af[i], bf[j], acc[i][j], 0, 0, 0);
        __syncthreads();
    }

    float tv = 0.f, qscale = 0.f;
    if constexpr (MODE == 3) {
        tv = tanhf(taup[0]);
        qscale = 0.08838834764831845f / (1.0f + tv);
    }
#pragma unroll
    for (int i = 0; i < 4; i++) {
#pragma unroll
        for (int j = 0; j < 4; j++) {
            int cc = col0 + wc * 64 + j * 16 + li;
            float bcol = (MODE == 2) ? 0.f : bias[cc];
#pragma unroll
            for (int r = 0; r < 4; r++) {
                int row = row0 + wr * 64 + i * 16 + g * 4 + r;
                if (MODE == 0 && row >= M) continue;
                float v = acc[i][j][r];
                if constexpr (MODE == 2) v += bias[row]; else v += bcol;
                size_t idx = (size_t)bz * sC + (size_t)row * N + cc;
                if constexpr (MODE == 0) ((float*)Cv)[idx] = v;
                else if constexpr (MODE == 1 || MODE == 2) ((f16*)Cv)[idx] = (f16)v;
                else if constexpr (MODE == 3) {
                    v = (v + tv * (float)extra[(size_t)bz * sE + (size_t)row * N + cc]) * qscale;
                    ((f16*)Cv)[idx] = (f16)v;
                } else ((float*)Cv)[idx] = v;
            }
        }
    }
}

// --------------------------- caption upsample ---------------------------
__global__ __launch_bounds__(256) void upsample_k(const float* __restrict__ Wup,
                                                  const float* __restrict__ CH,
                                                  f16* __restrict__ CU) {
    const int u = blockIdx.x, b = blockIdx.y;
    const float* ch = CH + (size_t)b * KC_ * HD_;
    float w[KC_];
#pragma unroll
    for (int c = 0; c < KC_; c++) w[c] = Wup[u * KC_ + c];
    f16* out = CU + ((size_t)b * NQ_ + u) * HD_;
#pragma unroll
    for (int t = 0; t < 4; t++) {
        int i = threadIdx.x + t * 256;
        float acc = 0.f;
#pragma unroll
        for (int c = 0; c < KC_; c++) acc += w[c] * ch[c * HD_ + i];
        out[i] = (f16)acc;
    }
}

// --------------------------- fused attention (v3) ---------------------------
// 2048 blocks x 512 thr (8 waves). Block = 32 q-rows of one (b,h).
// XCD swizzle: wgid = ((pair>>3)*32 + j)*8 + (pair&7) -> all 32 q-blocks of a
// (b,h) pair run consecutively on one XCD (round-robin %8 heuristic).
// Wave w: QK^T for keys [w*128,(w+1)*128) over all 32 rows (S = 16 f32x4);
// PV for d-cols [w*16,(w+1)*16) over all 1024 keys.
// LN over keys: shfl(li) + cross-wave via LDS scratch aliased into Plds[0:3KB]
// (dead before P written; 4-barrier schedule). No-max shifted softmax.
#define MFMA16(A_, B_, C_) __builtin_amdgcn_mfma_f32_16x16x32_f16(A_, B_, C_, 0, 0, 0)

__global__ __launch_bounds__(512) void attn_k(
    const f16* __restrict__ QE,   // [B,NQ,HD]  (scaled effective query)
    const f16* __restrict__ KH,   // [B,NK,HD]
    const f16* __restrict__ VT,   // [B,HD,NK]  (v-heads transposed)
    const float* __restrict__ lnw_g, const float* __restrict__ lnb_g,
    f16* __restrict__ ATT)        // [B,NQ,HD]
{
    __shared__ __align__(16) f16 Plds[32 * NK_];   // 64KB; XOR-swizzled 16B chunks
    float* redS = (float*)Plds;          // [8][32]  aliases P rows 0-1 (schedule-safe)
    float* redQ = redS + 256;            // [8][32]
    float* redL = redQ + 256;            // [8][32]

    const int tid = threadIdx.x;
    const int wave = tid >> 6, lane = tid & 63, g = lane >> 4, li = lane & 15;

    // swizzled block decode (bijective: wgid <-> (xcd, j, pairgrp))
    const int wgid = blockIdx.x;
    const int xcd = wgid & 7;
    const int n = wgid >> 3;
    const int pair = ((n >> 5) << 3) | xcd;   // b*8+h, 0..63
    const int b = pair >> 3, h = pair & 7;
    const int q0 = (n & 31) * 32;

    // ---- Q fragments: 2 row tiles (rows q0+li, q0+16+li) ----
    const f16* qp = QE + (size_t)(b * NQ_ + q0 + li) * HD_ + h * HS_ + g * 8;
    f16x8 a0[4], a1[4];
#pragma unroll
    for (int ks = 0; ks < 4; ks++) {
        a0[ks] = *(const f16x8*)(qp + ks * 32);
        a1[ks] = *(const f16x8*)(qp + (size_t)16 * HD_ + ks * 32);
    }

    // ---- QK^T: S[32 rows][128 keys] per wave; 32 units, 4-deep pipeline ----
    const f16* kp = KH + (size_t)(b * NK_ + wave * 128 + li) * HD_ + h * HS_ + g * 8;
    f32x4 s0[8], s1[8];
#pragma unroll
    for (int j = 0; j < 8; j++) { s0[j] = (f32x4){0.f,0.f,0.f,0.f}; s1[j] = s0[j]; }

    f16x8 kbA, kbB, kbC, kbD;
#define QK_LD(BUF, U) kb##BUF = *(const f16x8*)(kp + (size_t)((U) & 7) * 16 * HD_ + ((U) >> 3) * 32)
#define QK_FMA(BUF, U) do { \
        __builtin_amdgcn_s_setprio(1); \
        s0[(U) & 7] = MFMA16(a0[(U) >> 3], kb##BUF, s0[(U) & 7]); \
        s1[(U) & 7] = MFMA16(a1[(U) >> 3], kb##BUF, s1[(U) & 7]); \
        __builtin_amdgcn_s_setprio(0); \
    } while (0)

    QK_LD(A, 0); QK_LD(B, 1); QK_LD(C, 2); QK_LD(D, 3);
#pragma unroll
    for (int u = 0; u < 32; u += 4) {
        QK_FMA(A, u);     if (u + 4 < 32) QK_LD(A, u + 4);
        QK_FMA(B, u + 1); if (u + 5 < 32) QK_LD(B, u + 5);
        QK_FMA(C, u + 2); if (u + 6 < 32) QK_LD(C, u + 6);
        QK_FMA(D, u + 3); if (u + 7 < 32) QK_LD(D, u + 7);
    }
    // lane holds S[row = t*16 + g*4+r][key = wave*128 + j*16 + li], t=0,1

    // ---- ln weights for this wave's keys ----
    float lw[8], lb[8];
#pragma unroll
    for (int j = 0; j < 8; j++) {
        int key = wave * 128 + j * 16 + li;
        lw[j] = lnw_g[key];
        lb[j] = lnb_g[key];
    }

    // ---- per-wave partial mean/var over keys ----
    float ps0[4] = {0,0,0,0}, pq0[4] = {0,0,0,0}, ps1[4] = {0,0,0,0}, pq1[4] = {0,0,0,0};
#pragma unroll
    for (int j = 0; j < 8; j++)
#pragma unroll
        for (int r = 0; r < 4; r++) {
            float x0 = s0[j][r]; ps0[r] += x0; pq0[r] += x0 * x0;
            float x1 = s1[j][r]; ps1[r] += x1; pq1[r] += x1 * x1;
        }
#pragma unroll
    for (int m = 1; m < 16; m <<= 1)
#pragma unroll
        for (int r = 0; r < 4; r++) {
            ps0[r] += __shfl_xor(ps0[r], m, 64); pq0[r] += __shfl_xor(pq0[r], m, 64);
            ps1[r] += __shfl_xor(ps1[r], m, 64); pq1[r] += __shfl_xor(pq1[r], m, 64);
        }
    if (li == 0)
#pragma unroll
        for (int r = 0; r < 4; r++) {
            redS[wave * 32 + g * 4 + r] = ps0[r];      redQ[wave * 32 + g * 4 + r] = pq0[r];
            redS[wave * 32 + 16 + g * 4 + r] = ps1[r]; redQ[wave * 32 + 16 + g * 4 + r] = pq1[r];
        }
    __syncthreads();   // bar1: stats ready

    float mu0[4], rs0[4], mu1[4], rs1[4];
#pragma unroll
    for (int r = 0; r < 4; r++) {
        float s1a = 0.f, s2a = 0.f, s1b = 0.f, s2b = 0.f;
#pragma unroll
        for (int w = 0; w < 8; w++) {
            s1a += redS[w * 32 + g * 4 + r];      s2a += redQ[w * 32 + g * 4 + r];
            s1b += redS[w * 32 + 16 + g * 4 + r]; s2b += redQ[w * 32 + 16 + g * 4 + r];
        }
        float ma = s1a * (1.f / 1024.f), mb = s1b * (1.f / 1024.f);
        mu0[r] = ma; rs0[r] = rsqrtf(s2a * (1.f / 1024.f) - ma * ma + 1e-5f);
        mu1[r] = mb; rs1[r] = rsqrtf(s2b * (1.f / 1024.f) - mb * mb + 1e-5f);
    }

    // ---- LN + shifted exp (in-place into s) + row-sum ----
    float sm0[4] = {0,0,0,0}, sm1[4] = {0,0,0,0};
#pragma unroll
    for (int j = 0; j < 8; j++)
#pragma unroll
        for (int r = 0; r < 4; r++) {
            float x0 = (s0[j][r] - mu0[r]) * rs0[r] * lw[j] + lb[j];
            float e0 = __expf(fminf(x0, 11.f) - 4.f);
            s0[j][r] = e0; sm0[r] += e0;
            float x1 = (s1[j][r] - mu1[r]) * rs1[r] * lw[j] + lb[j];
            float e1 = __expf(fminf(x1, 11.f) - 4.f);
            s1[j][r] = e1; sm1[r] += e1;
        }
#pragma unroll
    for (int m = 1; m < 16; m <<= 1)
#pragma unroll
        for (int r = 0; r < 4; r++) {
            sm0[r] += __shfl_xor(sm0[r], m, 64);
            sm1[r] += __shfl_xor(sm1[r], m, 64);
        }
    if (li == 0)
#pragma unroll
        for (int r = 0; r < 4; r++) {
            redL[wave * 32 + g * 4 + r] = sm0[r];
            redL[wave * 32 + 16 + g * 4 + r] = sm1[r];
        }
    __syncthreads();   // bar2: redL ready

    float ls0[4], ls1[4];
#pragma unroll
    for (int r = 0; r < 4; r++) {
        float la = 0.f, lbs = 0.f;
#pragma unroll
        for (int w = 0; w < 8; w++) {
            la += redL[w * 32 + g * 4 + r];
            lbs += redL[w * 32 + 16 + g * 4 + r];
        }
        ls0[r] = la; ls1[r] = lbs;
    }
    __syncthreads();   // bar3: all reds consumed; safe to overwrite with P

    // ---- P write (swizzled f16) ----
#pragma unroll
    for (int j = 0; j < 8; j++) {
        int key = wave * 128 + j * 16 + li;
        int chunk = key >> 3, sub = key & 7;
#pragma unroll
        for (int r = 0; r < 4; r++) {
            int row0 = g * 4 + r, row1 = 16 + g * 4 + r;
            Plds[row0 * NK_ + ((chunk ^ (row0 & 7)) << 3) + sub] = (f16)s0[j][r];
            Plds[row1 * NK_ + ((chunk ^ (row1 & 7)) << 3) + sub] = (f16)s1[j][r];
        }
    }
    __syncthreads();   // bar4: P ready

    // ---- PV: O[32 rows][16 d] per wave; 32 ks units, 4-deep pipeline ----
    const f16* vp = VT + (size_t)(b * HD_ + h * HS_ + wave * 16 + li) * NK_ + g * 8;
    f32x4 o0a = (f32x4){0.f,0.f,0.f,0.f}, o0b = o0a, o1a = o0a, o1b = o0a;
    f16x8 pa0A, pa1A, vA, pa0B, pa1B, vB, pa0C, pa1C, vC, pa0D, pa1D, vD;
#define PV_LD(BUF, U) do { \
        size_t _c = (size_t)((((U) * 4 + g) ^ (li & 7)) << 3); \
        pa0##BUF = *(const f16x8*)&Plds[(size_t)li * NK_ + _c]; \
        pa1##BUF = *(const f16x8*)&Plds[(size_t)(16 + li) * NK_ + _c]; \
        v##BUF   = *(const f16x8*)(vp + (size_t)(U) * 32); \
    } while (0)
#define PV_FMA(BUF, O0, O1) do { \
        __builtin_amdgcn_s_setprio(1); \
        O0 = MFMA16(pa0##BUF, v##BUF, O0); \
        O1 = MFMA16(pa1##BUF, v##BUF, O1); \
        __builtin_amdgcn_s_setprio(0); \
    } while (0)

    PV_LD(A, 0); PV_LD(B, 1); PV_LD(C, 2); PV_LD(D, 3);
#pragma unroll
    for (int u = 0; u < 32; u += 4) {
        PV_FMA(A, o0a, o1a); if (u + 4 < 32) PV_LD(A, u + 4);
        PV_FMA(B, o0b, o1b); if (u + 5 < 32) PV_LD(B, u + 5);
        PV_FMA(C, o0a, o1a); if (u + 6 < 32) PV_LD(C, u + 6);
        PV_FMA(D, o0b, o1b); if (u + 7 < 32) PV_LD(D, u + 7);
    }

    // ---- normalize + store: rows t*16+g*4+r, col wave*16+li ----
    f16* op = ATT + (size_t)(b * NQ_ + q0) * HD_ + h * HS_ + wave * 16 + li;
#pragma unroll
    for (int r = 0; r < 4; r++) {
        int row0 = g * 4 + r, row1 = 16 + g * 4 + r;
        op[(size_t)row0 * HD_] = (f16)((o0a[r] + o0b[r]) / ls0[r]);
        op[(size_t)row1 * HD_] = (f16)((o1a[r] + o1b[r]) / ls1[r]);
    }
}

// --------------------------- launcher ---------------------------
extern "C" void kernel_launch(void* const* d_in, const int* in_sizes, int n_in,
                              void* d_out, int out_size, void* d_ws, size_t ws_size,
                              hipStream_t stream) {
    const float* v   = (const float*)d_in[0];
    const float* k   = (const float*)d_in[1];
    const float* q   = (const float*)d_in[2];
    const float* c   = (const float*)d_in[3];
    const float* Wv  = (const float*)d_in[4];
    const float* bv  = (const float*)d_in[5];
    const float* Wk  = (const float*)d_in[6];
    const float* bk  = (const float*)d_in[7];
    const float* Wq  = (const float*)d_in[8];
    const float* bq  = (const float*)d_in[9];
    const float* Wc  = (const float*)d_in[10];
    const float* bc  = (const float*)d_in[11];
    const float* Wm  = (const float*)d_in[12];
    const float* bm  = (const float*)d_in[13];
    const float* Wup = (const float*)d_in[14];
    const float* lnw = (const float*)d_in[15];
    const float* lnb = (const float*)d_in[16];
    const float* tau = (const float*)d_in[17];

    const size_t NE  = (size_t)B_ * NK_ * HD_;   // 8M elements
    const size_t NW  = (size_t)HD_ * HD_;        // 1M
    const size_t NC  = (size_t)B_ * KC_ * HD_;   // 256K

    const size_t REQUIRED = 95944704;            // 91.5 MB
    if (ws_size < REQUIRED) {                    // diagnostic sentinel, no fault
        fill_sentinel<<<dim3((out_size + 255) / 256), dim3(256), 0, stream>>>((float*)d_out, out_size);
        return;
    }
    char* ws = (char*)d_ws;
    f16*  k16  = (f16*)(ws + 0);                 // slotA: k16 -> QE
    f16*  QE   = (f16*)(ws + 0);
    f16*  v16  = (f16*)(ws + 16777216);          // slotB: v16 -> CU16
    f16*  CU16 = (f16*)(ws + 16777216);
    f16*  q16  = (f16*)(ws + 33554432);          // slotC: q16 -> ATT
    f16*  ATT  = (f16*)(ws + 33554432);
    f16*  c16  = (f16*)(ws + 50331648);
    float* CHf = (float*)(ws + 50855936);
    f16*  wk16 = (f16*)(ws + 51904512);
    f16*  wq16 = (f16*)(ws + 54001664);
    f16*  wv16 = (f16*)(ws + 56098816);
    f16*  wc16 = (f16*)(ws + 58195968);
    f16*  wm16 = (f16*)(ws + 60293120);
    f16*  KH   = (f16*)(ws + 62390272);
    f16*  VT   = (f16*)(ws + 79167488);

    dim3 blk(256);
    auto cvt = [&](const float* in, f16* out, size_t n) {
        cvt_f32_f16<<<dim3((unsigned)(n / 1024)), blk, 0, stream>>>(in, out, (int)(n / 4));
    };
    cvt(k, k16, NE);
    cvt(v, v16, NE);
    cvt(q, q16, NE);
    cvt(c, c16, NC);
    cvt(Wk, wk16, NW);
    cvt(Wq, wq16, NW);
    cvt(Wv, wv16, NW);
    cvt(Wc, wc16, NW);
    cvt(Wm, wm16, NW);

    // KH[b,key,hd] = k·Wk^T + bk
    gemm_nt<1><<<dim3(8, 8, 8), blk, 0, stream>>>(k16, (long long)NK_ * HD_, wk16, 0,
        KH, (long long)NK_ * HD_, NK_, HD_, HD_, bk, nullptr, 0, nullptr);
    // VT[b,hd,key] = (v·Wv^T + bv)^T  (Wv as A-operand)
    gemm_nt<2><<<dim3(8, 8, 8), blk, 0, stream>>>(wv16, 0, v16, (long long)NK_ * HD_,
        VT, (long long)HD_ * NK_, HD_, NK_, HD_, bv, nullptr, 0, nullptr);
    // CH[b,c,hd] = c·Wc^T + bc (fp32)
    gemm_nt<0><<<dim3(8, 1, 8), blk, 0, stream>>>(c16, (long long)KC_ * HD_, wc16, 0,
        CHf, (long long)KC_ * HD_, KC_, HD_, HD_, bc, nullptr, 0, nullptr);
    // CU = Wup · CH  (f16)
    upsample_k<<<dim3(NQ_, B_), blk, 0, stream>>>(Wup, CHf, CU16);
    // QE[b,q,hd] = (q·Wq^T + bq + t·CU) * inv_sqrt_d/(1+t)
    gemm_nt<3><<<dim3(8, 8, 8), blk, 0, stream>>>(q16, (long long)NQ_ * HD_, wq16, 0,
        QE, (long long)NQ_ * HD_, NQ_, HD_, HD_, bq, CU16, (long long)NQ_ * HD_, tau);
    // fused attention -> ATT[b,q,hd] (f16); 2048 blocks, 512 threads
    attn_k<<<dim3(2048), dim3(512), 0, stream>>>(QE, KH, VT, lnw, lnb, ATT);
    // out = ATT·Wm^T + bm (fp32)
    gemm_nt<4><<<dim3(8, 8, 8), blk, 0, stream>>>(ATT, (long long)NQ_ * HD_, wm16, 0,
        d_out, (long long)NQ_ * HD_, NQ_, HD_, HD_, bm, nullptr, 0, nullptr);
}